// Round 6
// baseline (232.583 us; speedup 1.0000x reference)
//
#include <hip/hip_runtime.h>

#define WIN      60
#define OFFSET_D 40
#define TRUNC    21
#define EPS      1e-8f
#define BB       64
#define TT       4000
#define KK       100
#define TK       (TT*KK)          // 400000 elements per batch
#define CHUNK    16384            // 256 threads * 4 * 16
#define CHB      25               // ceil(TK/CHUNK); last chunk = 6784 elems
#define NNEG     (BB*CHB)         // 1600 neg blocks
#define NBLK     (BB + NNEG)      // 1664 total blocks (< 2048 residency slots)

__device__ __forceinline__ float clamp1(float x) {
    return fminf(fmaxf(1.0f - x, EPS), 1.0f);
}

// d_ws layout: [0..7] counter (zeroed by memset node); [8..] NBLK doubles of partials.
// blocks [0,BB): positive term (1 wave). blocks [BB,NBLK): neg chunk.
// Last block to finish reduces all partials and writes the scalar (no 2nd kernel).
__global__ __launch_bounds__(256) void fused_kernel(const float* __restrict__ X,
                                                    const int* __restrict__ lengths,
                                                    const int* __restrict__ tgt,
                                                    const int* __restrict__ w_end,
                                                    unsigned int* __restrict__ counter,
                                                    double* __restrict__ partials,
                                                    float* __restrict__ out) {
    const int bid = blockIdx.x;
    const int tid = threadIdx.x;
    double my_partial = 0.0;
    bool have_partial = (tid == 0);

    if (bid >= BB) {
        // ---------------- negative term chunk ----------------
        const int nb   = bid - BB;
        const int b    = nb / CHB;
        const int c    = nb - b * CHB;
        const int s    = c * CHUNK;
        const int lenK = lengths[b] * KK;       // multiple of 4 (KK=100)
        const float* __restrict__ base = X + (size_t)b * TK;

        float a0 = 0.f, a1 = 0.f;

        if (s + CHUNK <= lenK) {
            // fully-valid chunk: 4 phases of {4 float4 loads, 2 logs (8-elem groups)}
            const float* __restrict__ p = base + s + (tid << 2);
            #pragma unroll
            for (int ph = 0; ph < 4; ++ph) {
                float4 v[4];
                #pragma unroll
                for (int k = 0; k < 4; ++k)
                    v[k] = *reinterpret_cast<const float4*>(p + (ph * 4 + k) * 1024);
                const float pr0 = ((clamp1(v[0].x) * clamp1(v[0].y)) *
                                   (clamp1(v[0].z) * clamp1(v[0].w))) *
                                  ((clamp1(v[1].x) * clamp1(v[1].y)) *
                                   (clamp1(v[1].z) * clamp1(v[1].w)));
                const float pr1 = ((clamp1(v[2].x) * clamp1(v[2].y)) *
                                   (clamp1(v[2].z) * clamp1(v[2].w))) *
                                  ((clamp1(v[3].x) * clamp1(v[3].y)) *
                                   (clamp1(v[3].z) * clamp1(v[3].w)));
                a0 -= __logf(pr0);
                a1 -= __logf(pr1);
            }
        } else if (s < lenK) {
            // boundary chunk: per-lane predicated, log per float4
            const int m0 = s + (tid << 2);
            #pragma unroll
            for (int k = 0; k < 16; ++k) {
                const int m = m0 + k * 1024;
                if (m < lenK) {
                    const float4 v = *reinterpret_cast<const float4*>(base + m);
                    a0 -= __logf((clamp1(v.x) * clamp1(v.y)) *
                                 (clamp1(v.z) * clamp1(v.w)));
                }
            }
        }
        float local = a0 + a1;

        #pragma unroll
        for (int off = 32; off > 0; off >>= 1) local += __shfl_down(local, off);
        __shared__ float wsum[4];
        if ((tid & 63) == 0) wsum[tid >> 6] = local;
        __syncthreads();
        if (tid == 0)
            my_partial = (double)(wsum[0] + wsum[1] + wsum[2] + wsum[3]);
    } else if (tid < 64) {
        // ---------------- positive term: one wave per batch ----------------
        const int b  = bid;
        const int ts = max(0, w_end[b] + OFFSET_D - WIN);
        const int te = min(ts + WIN, lengths[b]);
        const int Lw = te - ts;                 // >= 21 always
        const int tg = tgt[b];

        float g = 0.0f;
        if (tid < TRUNC) {
            const float x = (tid - 10) * (1.0f / 9.0f);
            g = __expf(-0.5f * x * x);
        }
        float gs = g;
        #pragma unroll
        for (int off = 32; off > 0; off >>= 1) gs += __shfl_down(gs, off);
        gs = __shfl(gs, 0);
        const float gnorm = g / gs;

        float w = 0.0f, sub = 0.0f;
        if (tid < Lw) {                         // Lw <= 60 < 64
            const float xw = X[(size_t)b * TK + (size_t)(ts + tid) * KK + tg];
            w = xw;
            sub = -__logf(clamp1(xw));
        }

        float sm = 0.0f;                        // smoothed[i] = sum_u gn[u]*win[i-9+u]
        #pragma unroll
        for (int u = 0; u < TRUNC; ++u) {
            const float gu = __shfl(gnorm, u);
            const int   j  = tid - 9 + u;
            const float wv = __shfl(w, j & 63);
            sm += gu * (((unsigned)j < (unsigned)WIN) ? wv : 0.0f);
        }

        float cand = (tid < Lw) ? fminf(fmaxf(sm, EPS), 1.0f) : 0.0f;
        #pragma unroll
        for (int off = 32; off > 0; off >>= 1) {
            sub  += __shfl_down(sub, off);
            cand  = fmaxf(cand, __shfl_down(cand, off));
        }
        if (tid == 0)
            my_partial = (double)(-__logf(cand) - sub);
    }

    // ---- publish partial, last-done block reduces everything ----
    __shared__ bool is_last;
    if (have_partial) {
        partials[bid] = my_partial;
        __threadfence();                         // partial visible before signal
        const unsigned int old = atomicAdd(counter, 1u);
        is_last = (old == NBLK - 1);
    }
    __syncthreads();
    if (!is_last) return;
    __threadfence();                             // acquire all partials

    double s = 0.0;
    for (int i = tid; i < NBLK; i += 256) s += partials[i];
    #pragma unroll
    for (int off = 32; off > 0; off >>= 1) s += __shfl_down(s, off);
    __shared__ double dsum[4];
    if ((tid & 63) == 0) dsum[tid >> 6] = s;
    __syncthreads();
    if (tid == 0)
        out[0] = (float)(dsum[0] + dsum[1] + dsum[2] + dsum[3]);
}

extern "C" void kernel_launch(void* const* d_in, const int* in_sizes, int n_in,
                              void* d_out, int out_size, void* d_ws, size_t ws_size,
                              hipStream_t stream) {
    const float* X        = (const float*)d_in[0];
    const int*   lengths  = (const int*)d_in[1];
    const int*   tgt      = (const int*)d_in[2];
    const int*   w_end    = (const int*)d_in[3];
    float*       out      = (float*)d_out;
    unsigned int* counter = (unsigned int*)d_ws;
    double*      partials = (double*)((char*)d_ws + 8);

    hipMemsetAsync(counter, 0, 8, stream);       // zero the done-counter (graph-safe)
    fused_kernel<<<NBLK, 256, 0, stream>>>(X, lengths, tgt, w_end, counter, partials, out);
}

// Round 7
// 149.885 us; speedup vs baseline: 1.5517x; 1.5517x over previous
//
#include <hip/hip_runtime.h>

#define WIN      60
#define OFFSET_D 40
#define TRUNC    21
#define EPS      1e-8f
#define BB       64
#define TT       4000
#define KK       100
#define TK       (TT*KK)          // 400000 elements per batch
#define CHUNK    12288            // 256 threads * 4 * 12
#define CHB      33               // ceil(TK/CHUNK); last chunk = 6784 elems
#define NNEG     (BB*CHB)         // 2112 neg blocks
#define NPART    (BB + NNEG)      // + 64 pos slots = 2176

__device__ __forceinline__ float clamp1(float x) {
    return fminf(fmaxf(1.0f - x, EPS), 1.0f);
}

// blocks [0,BB): positive term (1 wave, shuffle-only).
// blocks [BB, BB+NNEG): negative-term chunk (R5-proven structure; no fences,
// no cross-block signaling — that regressed 4x in R6 via L2-flush storms).
__global__ __launch_bounds__(256) void fused_kernel(const float* __restrict__ X,
                                                    const int* __restrict__ lengths,
                                                    const int* __restrict__ tgt,
                                                    const int* __restrict__ w_end,
                                                    double* __restrict__ partials) {
    const int bid = blockIdx.x;
    const int tid = threadIdx.x;

    if (bid >= BB) {
        // ---------------- negative term chunk ----------------
        const int nb   = bid - BB;
        const int b    = nb / CHB;
        const int c    = nb - b * CHB;
        const int s    = c * CHUNK;
        const int lenK = lengths[b] * KK;       // multiple of 4 (KK=100)
        const float* __restrict__ base = X + (size_t)b * TK;

        float a0 = 0.f, a1 = 0.f;

        if (s + CHUNK <= lenK) {
            // fully-valid chunk: two phases of {6 float4 loads, 3 logs (8-elem groups)}
            const float* __restrict__ p = base + s + (tid << 2);
            #pragma unroll
            for (int ph = 0; ph < 2; ++ph) {
                float4 v[6];
                #pragma unroll
                for (int k = 0; k < 6; ++k)
                    v[k] = *reinterpret_cast<const float4*>(p + (ph * 6 + k) * 1024);
                #pragma unroll
                for (int k = 0; k < 3; ++k) {
                    const float pr = (((clamp1(v[2*k].x)   * clamp1(v[2*k].y)) *
                                       (clamp1(v[2*k].z)   * clamp1(v[2*k].w))) *
                                      ((clamp1(v[2*k+1].x) * clamp1(v[2*k+1].y)) *
                                       (clamp1(v[2*k+1].z) * clamp1(v[2*k+1].w))));
                    if (k & 1) a1 -= __logf(pr); else a0 -= __logf(pr);
                }
            }
        } else if (s < lenK) {
            // boundary chunk: per-lane predicated, log per float4
            const int m0 = s + (tid << 2);
            #pragma unroll
            for (int k = 0; k < 12; ++k) {
                const int m = m0 + k * 1024;
                if (m < lenK) {
                    const float4 v = *reinterpret_cast<const float4*>(base + m);
                    a0 -= __logf((clamp1(v.x) * clamp1(v.y)) *
                                 (clamp1(v.z) * clamp1(v.w)));
                }
            }
        }
        float local = a0 + a1;

        #pragma unroll
        for (int off = 32; off > 0; off >>= 1) local += __shfl_down(local, off);
        __shared__ float wsum[4];
        if ((tid & 63) == 0) wsum[tid >> 6] = local;
        __syncthreads();
        if (tid == 0)
            partials[bid] = (double)(wsum[0] + wsum[1] + wsum[2] + wsum[3]);
        return;
    }

    // ---------------- positive term: one wave per batch, shuffle-only ----------------
    if (tid >= 64) return;                      // single wave; no barriers below
    const int b  = bid;

    const int ts = max(0, w_end[b] + OFFSET_D - WIN);
    const int te = min(ts + WIN, lengths[b]);
    const int Lw = te - ts;                     // >= 21 always
    const int tg = tgt[b];

    // normalized truncated Gaussian: lane u (<21) holds gn[u]
    float g = 0.0f;
    if (tid < TRUNC) {
        const float x = (tid - 10) * (1.0f / 9.0f);
        g = __expf(-0.5f * x * x);
    }
    float gs = g;
    #pragma unroll
    for (int off = 32; off > 0; off >>= 1) gs += __shfl_down(gs, off);
    gs = __shfl(gs, 0);
    const float gnorm = g / gs;

    // ragged zero-padded window + subtraction term
    float w = 0.0f, sub = 0.0f;
    if (tid < Lw) {                             // Lw <= 60 < 64
        const float xw = X[(size_t)b * TK + (size_t)(ts + tid) * KK + tg];
        w = xw;
        sub = -__logf(clamp1(xw));
    }

    // 'same' conv: smoothed[i] = sum_u gn[u] * win[i-9+u]
    float sm = 0.0f;
    #pragma unroll
    for (int u = 0; u < TRUNC; ++u) {
        const float gu = __shfl(gnorm, u);
        const int   j  = tid - 9 + u;
        const float wv = __shfl(w, j & 63);
        sm += gu * (((unsigned)j < (unsigned)WIN) ? wv : 0.0f);  // w already 0 for j>=Lw
    }

    float cand = (tid < Lw) ? fminf(fmaxf(sm, EPS), 1.0f) : 0.0f;
    #pragma unroll
    for (int off = 32; off > 0; off >>= 1) {
        sub  += __shfl_down(sub, off);
        cand  = fmaxf(cand, __shfl_down(cand, off));
    }
    if (tid == 0)
        partials[bid] = (double)(-__logf(cand) - sub);
}

// ---- finalize: deterministic reduce of all partials -> scalar
__global__ __launch_bounds__(256) void finalize_kernel(const double* __restrict__ p,
                                                       float* __restrict__ out) {
    double s = 0.0;
    for (int i = threadIdx.x; i < NPART; i += 256) s += p[i];
    #pragma unroll
    for (int off = 32; off > 0; off >>= 1) s += __shfl_down(s, off);
    __shared__ double wsum[4];
    if ((threadIdx.x & 63) == 0) wsum[threadIdx.x >> 6] = s;
    __syncthreads();
    if (threadIdx.x == 0)
        out[0] = (float)(wsum[0] + wsum[1] + wsum[2] + wsum[3]);
}

extern "C" void kernel_launch(void* const* d_in, const int* in_sizes, int n_in,
                              void* d_out, int out_size, void* d_ws, size_t ws_size,
                              hipStream_t stream) {
    const float* X        = (const float*)d_in[0];
    const int*   lengths  = (const int*)d_in[1];
    const int*   tgt      = (const int*)d_in[2];
    const int*   w_end    = (const int*)d_in[3];
    float*       out      = (float*)d_out;
    double*      partials = (double*)d_ws;     // NPART doubles = 17.4 KB

    fused_kernel<<<BB + NNEG, 256, 0, stream>>>(X, lengths, tgt, w_end, partials);
    finalize_kernel<<<1, 256, 0, stream>>>(partials, out);
}